// Round 1
// baseline (478.730 us; speedup 1.0000x reference)
//
#include <hip/hip_runtime.h>

// x: (4, 32, 512, 512) fp32; bias: (1,32,1,1) fp32
// out: G1 | G2 | G3 concatenated, each (4,32,512,512) fp32
//
// G1[h,w] = (h>=1 && w>=1) ? exp(-(x[h-1,w-1]-x[h,w])^2)+b : b
// G2[h,w] = (w>=1)          ? exp(-(x[h,w-1]  -x[h,w])^2)+b : b
// G3[h,w] = (h<=510 && w>=1)? exp(-(x[h+1,w-1]-x[h,w])^2)+b : b
//
// Memory-bound: 128 MiB read + 384 MiB write => ~85 us at 6.3 TB/s.

#define IMG_W 512
#define IMG_H 512
#define PLANE (IMG_W * IMG_H)
#define N_IMG 128            // 4 * 32
#define N_ELEM (N_IMG * PLANE)

__global__ __launch_bounds__(256)
void embeded_gate_kernel(const float* __restrict__ x,
                         const float* __restrict__ bias,
                         float* __restrict__ out) {
    int tid = blockIdx.x * blockDim.x + threadIdx.x;
    // one thread per float4 group: 128 groups per row
    int w4  = tid & 127;          // float4 index within row
    int row = tid >> 7;           // global row index (img*512 + h)
    int h   = row & 511;
    int img = row >> 9;           // n*32 + c
    int c   = img & 31;
    int w0  = w4 << 2;            // first column of this group

    const float b = bias[c];

    int rowc = img * PLANE + h * IMG_W;
    int hu = (h > 0)   ? h - 1 : 0;     // clamped: result masked later
    int hd = (h < 511) ? h + 1 : 511;
    int wm = (w0 > 0)  ? w0 - 1 : 0;
    int rowu = img * PLANE + hu * IMG_W;
    int rowd = img * PLANE + hd * IMG_W;

    // aligned vector loads (coalesced, 16B/lane)
    const float4 cur = *(const float4*)(x + rowc + w0);
    const float4 up  = *(const float4*)(x + rowu + w0);
    const float4 dn  = *(const float4*)(x + rowd + w0);
    // the w0-1 scalars (L1/L2 hits — same cache lines as neighbor threads)
    const float upm = x[rowu + wm];
    const float cum = x[rowc + wm];
    const float dnm = x[rowd + wm];

    // shifted-by-one views covering columns [w0-1 .. w0+2]
    float us[4] = {upm, up.x, up.y, up.z};
    float cs[4] = {cum, cur.x, cur.y, cur.z};
    float ds[4] = {dnm, dn.x, dn.y, dn.z};
    float cc[4] = {cur.x, cur.y, cur.z, cur.w};

    const bool hok_u = (h > 0);
    const bool hok_d = (h < 511);

    float4 g1, g2, g3;
    float* p1 = &g1.x;
    float* p2 = &g2.x;
    float* p3 = &g3.x;

#pragma unroll
    for (int j = 0; j < 4; ++j) {
        const bool wok = (w0 + j) > 0;   // only j==0 of w4==0 fails
        float d1 = us[j] - cc[j];
        float d2 = cs[j] - cc[j];
        float d3 = ds[j] - cc[j];
        float e1 = __expf(-d1 * d1);
        float e2 = __expf(-d2 * d2);
        float e3 = __expf(-d3 * d3);
        p1[j] = (hok_u && wok) ? e1 + b : b;
        p2[j] = wok            ? e2 + b : b;
        p3[j] = (hok_d && wok) ? e3 + b : b;
    }

    *(float4*)(out + rowc + w0)               = g1;
    *(float4*)(out + N_ELEM + rowc + w0)      = g2;
    *(float4*)(out + 2 * N_ELEM + rowc + w0)  = g3;
}

extern "C" void kernel_launch(void* const* d_in, const int* in_sizes, int n_in,
                              void* d_out, int out_size, void* d_ws, size_t ws_size,
                              hipStream_t stream) {
    const float* x    = (const float*)d_in[0];
    const float* bias = (const float*)d_in[1];
    float* out        = (float*)d_out;

    const int total_vec = N_ELEM / 4;          // 8,388,608 threads
    const int block = 256;
    const int grid = total_vec / block;        // 32,768 blocks
    embeded_gate_kernel<<<grid, block, 0, stream>>>(x, bias, out);
}